// Round 1
// baseline (53454.102 us; speedup 1.0000x reference)
//
#include <hip/hip_runtime.h>

#define SEQ 65536
#define IN_DIM 64
#define H 128
#define G4 (4 * H) // 512 gate rows

__device__ __forceinline__ float fast_rcp(float x) { return __builtin_amdgcn_rcpf(x); }

__device__ __forceinline__ float sigmoid_f(float x) {
    x = fminf(fmaxf(x, -30.f), 30.f);
    return fast_rcp(1.f + __expf(-x));
}

__device__ __forceinline__ float tanh_f(float x) {
    x = fminf(fmaxf(x, -15.f), 15.f);
    float e = __expf(2.f * x);
    return (e - 1.f) * fast_rcp(e + 1.f);
}

// ---------------------------------------------------------------------------
// Phase A: x_gates[s][r] = dot(input[s], W_ih[r]) + b_ih[r] + b_hh[r]
// Memory-bound (128 MB write). W_ih (128 KB) is L2-resident after warmup.
// ---------------------------------------------------------------------------
__global__ __launch_bounds__(256) void xg_gemm(
    const float* __restrict__ x, const float* __restrict__ Wih,
    const float* __restrict__ bih, const float* __restrict__ bhh,
    float* __restrict__ xg)
{
    long long gid = (long long)blockIdx.x * 256 + threadIdx.x;
    int s = (int)(gid >> 9);  // / 512
    int r = (int)(gid & 511);
    const float* xr = x + (long long)s * IN_DIM;
    const float* wr = Wih + (long long)r * IN_DIM;
    float a0 = 0.f, a1 = 0.f, a2 = 0.f, a3 = 0.f;
#pragma unroll
    for (int k = 0; k < IN_DIM; k += 4) {
        float4 iv = *(const float4*)(xr + k);
        float4 wv = *(const float4*)(wr + k);
        a0 += wv.x * iv.x; a1 += wv.y * iv.y;
        a2 += wv.z * iv.z; a3 += wv.w * iv.w;
    }
    xg[gid] = (a0 + a1) + (a2 + a3) + bih[r] + bhh[r];
}

// ---------------------------------------------------------------------------
// Phase B: persistent single-workgroup LSTM scan.
// 512 threads = 8 waves on 1 CU. Thread t owns W_hh row t in 128 VGPRs.
// h[128] in LDS (broadcast ds_read_b128). c[j] lives in VGPRs of the o-gate
// threads (rows 384..511), which perform the cell update between barriers.
// USE_WS: x_gates prefetched from global scratch one step ahead.
// else:   x_gates computed on the fly from W_ih row held in 64 VGPRs.
// ---------------------------------------------------------------------------
template <bool USE_WS>
__global__ __launch_bounds__(512, 2) void lstm_scan(
    const float* __restrict__ x, const float* __restrict__ Wih,
    const float* __restrict__ Whh, const float* __restrict__ bih,
    const float* __restrict__ bhh, const float* __restrict__ Wlin,
    const float* __restrict__ blin, const float* __restrict__ xg_ws,
    float* __restrict__ out)
{
    __shared__ __align__(16) float sh_h[H];
    __shared__ __align__(16) float sh_g[G4];
    const int row = threadIdx.x;

    // W_hh row -> registers (compile-time indices only => SROA to VGPRs)
    float w[H];
#pragma unroll
    for (int k = 0; k < H; k += 4) {
        float4 wv = *(const float4*)(Whh + (long long)row * H + k);
        w[k] = wv.x; w[k + 1] = wv.y; w[k + 2] = wv.z; w[k + 3] = wv.w;
    }

    float wih_r[IN_DIM];
    if (!USE_WS) {
#pragma unroll
        for (int k = 0; k < IN_DIM; k += 4) {
            float4 wv = *(const float4*)(Wih + (long long)row * IN_DIM + k);
            wih_r[k] = wv.x; wih_r[k + 1] = wv.y;
            wih_r[k + 2] = wv.z; wih_r[k + 3] = wv.w;
        }
    }

    const float bsum = bih[row] + bhh[row];
    float c = 0.f;
    if (row < H) sh_h[row] = 0.f;

    // x-gate for t = 0
    float xg_cur;
    if (USE_WS) {
        xg_cur = xg_ws[row];
    } else {
        float a = bsum;
#pragma unroll
        for (int k = 0; k < IN_DIM; k += 4) {
            float4 iv = *(const float4*)(x + k);
            a += wih_r[k] * iv.x + wih_r[k + 1] * iv.y +
                 wih_r[k + 2] * iv.z + wih_r[k + 3] * iv.w;
        }
        xg_cur = a;
    }
    const bool is_g = (row >= 2 * H) && (row < 3 * H); // tanh gate
    __syncthreads();

    for (int t = 0; t < SEQ; ++t) {
        // prefetch / precompute next step's x-gate (independent of h)
        float xg_nxt = 0.f;
        if (USE_WS) {
            if (t + 1 < SEQ) xg_nxt = xg_ws[(size_t)(t + 1) * G4 + row];
        } else {
            if (t + 1 < SEQ) {
                const float* xr = x + (size_t)(t + 1) * IN_DIM;
                float a = bsum;
#pragma unroll
                for (int k = 0; k < IN_DIM; k += 4) {
                    float4 iv = *(const float4*)(xr + k);
                    a += wih_r[k] * iv.x + wih_r[k + 1] * iv.y +
                         wih_r[k + 2] * iv.z + wih_r[k + 3] * iv.w;
                }
                xg_nxt = a;
            }
        }

        // gates = xg + W_hh . h   (h broadcast from LDS, 4 accumulators)
        float a0 = 0.f, a1 = 0.f, a2 = 0.f, a3 = 0.f;
#pragma unroll
        for (int k = 0; k < H; k += 4) {
            float4 hv = *(const float4*)(sh_h + k);
            a0 += w[k] * hv.x;     a1 += w[k + 1] * hv.y;
            a2 += w[k + 2] * hv.z; a3 += w[k + 3] * hv.w;
        }
        float pre = xg_cur + ((a0 + a1) + (a2 + a3));
        float gv = is_g ? tanh_f(pre) : sigmoid_f(pre);
        sh_g[row] = gv;
        __syncthreads();

        // cell update on o-gate threads (their gv == o_j; c_j stays in VGPR)
        if (row >= 3 * H) {
            int j = row - 3 * H;
            float ig = sh_g[j];
            float fg = sh_g[H + j];
            float gg = sh_g[2 * H + j];
            c = fg * c + ig * gg;
            sh_h[j] = gv * tanh_f(c);
        }
        __syncthreads();
        xg_cur = xg_nxt;
    }

    // out = sigmoid(h . W_lin + b_lin)  -- one wave reduces
    if (row < 64) {
        float p = sh_h[row] * Wlin[row] + sh_h[row + 64] * Wlin[row + 64];
#pragma unroll
        for (int off = 32; off > 0; off >>= 1) p += __shfl_down(p, off);
        if (row == 0) out[0] = sigmoid_f(p + blin[0]);
    }
}

extern "C" void kernel_launch(void* const* d_in, const int* in_sizes, int n_in,
                              void* d_out, int out_size, void* d_ws, size_t ws_size,
                              hipStream_t stream)
{
    const float* x    = (const float*)d_in[0];
    const float* Wih  = (const float*)d_in[1];
    const float* Whh  = (const float*)d_in[2];
    const float* bih  = (const float*)d_in[3];
    const float* bhh  = (const float*)d_in[4];
    const float* Wlin = (const float*)d_in[5];
    const float* blin = (const float*)d_in[6];
    float* out = (float*)d_out;

    const size_t need = (size_t)SEQ * G4 * sizeof(float); // 128 MB
    if (ws_size >= need) {
        float* xg = (float*)d_ws;
        xg_gemm<<<(SEQ * G4) / 256, 256, 0, stream>>>(x, Wih, bih, bhh, xg);
        lstm_scan<true><<<1, 512, 0, stream>>>(x, Wih, Whh, bih, bhh, Wlin,
                                               blin, xg, out);
    } else {
        lstm_scan<false><<<1, 512, 0, stream>>>(x, Wih, Whh, bih, bhh, Wlin,
                                                blin, nullptr, out);
    }
}

// Round 2
// 38716.583 us; speedup vs baseline: 1.3807x; 1.3807x over previous
//
#include <hip/hip_runtime.h>

#define SEQ 65536
#define IN_DIM 64
#define H 128
#define G4 (4 * H) // 512 gate rows

typedef _Float16 half_t;
typedef half_t half2_t __attribute__((ext_vector_type(2)));
typedef half_t half8_t __attribute__((ext_vector_type(8)));

__device__ __forceinline__ float fast_rcp(float x) { return __builtin_amdgcn_rcpf(x); }

__device__ __forceinline__ float sigmoid_f(float x) {
    x = fminf(fmaxf(x, -30.f), 30.f);
    return fast_rcp(1.f + __expf(-x));
}

__device__ __forceinline__ float tanh_f(float x) {
    x = fminf(fmaxf(x, -15.f), 15.f);
    float e = __expf(2.f * x);
    return (e - 1.f) * fast_rcp(e + 1.f);
}

#if __has_builtin(__builtin_amdgcn_fdot2)
__device__ __forceinline__ float dot2(half2_t a, half2_t b, float c) {
    return __builtin_amdgcn_fdot2(a, b, c, false);
}
#else
__device__ __forceinline__ float dot2(half2_t a, half2_t b, float c) {
    return c + (float)a[0] * (float)b[0] + (float)a[1] * (float)b[1];
}
#endif

__device__ __forceinline__ half2_t pick2(half8_t v, int i0) {
    half2_t r; r[0] = v[i0]; r[1] = v[i0 + 1]; return r;
}

// convert 8 fp32 (two float4 loads) -> half8
__device__ __forceinline__ half8_t cvt8(const float* p) {
    float4 a = *(const float4*)p;
    float4 b = *(const float4*)(p + 4);
    half8_t r;
    r[0] = (half_t)a.x; r[1] = (half_t)a.y; r[2] = (half_t)a.z; r[3] = (half_t)a.w;
    r[4] = (half_t)b.x; r[5] = (half_t)b.y; r[6] = (half_t)b.z; r[7] = (half_t)b.w;
    return r;
}

// ---------------------------------------------------------------------------
// Phase A: x_gates[s][r] = dot(input[s], W_ih[r]) + b_ih[r] + b_hh[r]   (fp32)
// ---------------------------------------------------------------------------
__global__ __launch_bounds__(256) void xg_gemm(
    const float* __restrict__ x, const float* __restrict__ Wih,
    const float* __restrict__ bih, const float* __restrict__ bhh,
    float* __restrict__ xg)
{
    long long gid = (long long)blockIdx.x * 256 + threadIdx.x;
    int s = (int)(gid >> 9);
    int r = (int)(gid & 511);
    const float* xr = x + (long long)s * IN_DIM;
    const float* wr = Wih + (long long)r * IN_DIM;
    float a0 = 0.f, a1 = 0.f, a2 = 0.f, a3 = 0.f;
#pragma unroll
    for (int k = 0; k < IN_DIM; k += 4) {
        float4 iv = *(const float4*)(xr + k);
        float4 wv = *(const float4*)(wr + k);
        a0 += wv.x * iv.x; a1 += wv.y * iv.y;
        a2 += wv.z * iv.z; a3 += wv.w * iv.w;
    }
    xg[gid] = (a0 + a1) + (a2 + a3) + bih[r] + bhh[r];
}

// ---------------------------------------------------------------------------
// Phase B: persistent single-workgroup LSTM scan, f16 recurrent matvec.
// 512 threads = 8 waves on 1 CU. Thread t owns W_hh row t as 16 named half8
// variables (64 VGPRs, SROA-proof). h kept in LDS as f16 (256 B), read as
// half8 broadcast ds_read_b128 (16/thread/step). Gates/c/xg stay fp32.
// ---------------------------------------------------------------------------
template <bool USE_WS>
__global__ __launch_bounds__(512, 2) void lstm_scan(
    const float* __restrict__ x, const float* __restrict__ Wih,
    const float* __restrict__ Whh, const float* __restrict__ bih,
    const float* __restrict__ bhh, const float* __restrict__ Wlin,
    const float* __restrict__ blin, const float* __restrict__ xg_ws,
    float* __restrict__ out)
{
    __shared__ __align__(16) half_t sh_h[H];   // 256 B
    __shared__ __align__(16) float  sh_g[G4];  // 2 KB, post-activation gates
    const int row = threadIdx.x;
    const float* wrow = Whh + (long long)row * H;

    // W_hh row -> 16 named half8 registers (64 VGPRs)
    half8_t w0  = cvt8(wrow + 0),   w1  = cvt8(wrow + 8);
    half8_t w2  = cvt8(wrow + 16),  w3  = cvt8(wrow + 24);
    half8_t w4  = cvt8(wrow + 32),  w5  = cvt8(wrow + 40);
    half8_t w6  = cvt8(wrow + 48),  w7  = cvt8(wrow + 56);
    half8_t w8  = cvt8(wrow + 64),  w9  = cvt8(wrow + 72);
    half8_t w10 = cvt8(wrow + 80),  w11 = cvt8(wrow + 88);
    half8_t w12 = cvt8(wrow + 96),  w13 = cvt8(wrow + 104);
    half8_t w14 = cvt8(wrow + 112), w15 = cvt8(wrow + 120);

    const float bsum = bih[row] + bhh[row];
    float c = 0.f;
    if (row < H) sh_h[row] = (half_t)0.f;

    // x-gate for t = 0
    float xg_cur;
    if (USE_WS) {
        xg_cur = xg_ws[row];
    } else {
        float a = bsum;
        const float* wir = Wih + (long long)row * IN_DIM;
#pragma unroll
        for (int k = 0; k < IN_DIM; k += 4) {
            float4 iv = *(const float4*)(x + k);
            float4 wv = *(const float4*)(wir + k);
            a += wv.x * iv.x + wv.y * iv.y + wv.z * iv.z + wv.w * iv.w;
        }
        xg_cur = a;
    }
    const bool is_g = (row >= 2 * H) && (row < 3 * H); // tanh gate
    __syncthreads();

    const half8_t* hch = (const half8_t*)sh_h; // 16 chunks of 8 f16

    for (int t = 0; t < SEQ; ++t) {
        // prefetch next step's x-gate (independent of h; hides global latency)
        float xg_nxt = 0.f;
        if (USE_WS) {
            if (t + 1 < SEQ) xg_nxt = xg_ws[(size_t)(t + 1) * G4 + row];
        } else {
            if (t + 1 < SEQ) {
                const float* xr = x + (size_t)(t + 1) * IN_DIM;
                const float* wir = Wih + (long long)row * IN_DIM;
                float a = bsum;
#pragma unroll
                for (int k = 0; k < IN_DIM; k += 4) {
                    float4 iv = *(const float4*)(xr + k);
                    float4 wv = *(const float4*)(wir + k);
                    a += wv.x * iv.x + wv.y * iv.y + wv.z * iv.z + wv.w * iv.w;
                }
                xg_nxt = a;
            }
        }

        // gates = xg + W_hh . h   (f16 dot2, fp32 accumulate, 4 chains)
        float a0 = 0.f, a1 = 0.f, a2 = 0.f, a3 = 0.f;
#define DOTC(WV, CI)                                                     \
        {   half8_t hv = hch[CI];                                        \
            a0 = dot2(pick2(WV, 0), pick2(hv, 0), a0);                   \
            a1 = dot2(pick2(WV, 2), pick2(hv, 2), a1);                   \
            a2 = dot2(pick2(WV, 4), pick2(hv, 4), a2);                   \
            a3 = dot2(pick2(WV, 6), pick2(hv, 6), a3); }
        DOTC(w0, 0)  DOTC(w1, 1)  DOTC(w2, 2)   DOTC(w3, 3)
        DOTC(w4, 4)  DOTC(w5, 5)  DOTC(w6, 6)   DOTC(w7, 7)
        DOTC(w8, 8)  DOTC(w9, 9)  DOTC(w10, 10) DOTC(w11, 11)
        DOTC(w12, 12) DOTC(w13, 13) DOTC(w14, 14) DOTC(w15, 15)
#undef DOTC
        float pre = xg_cur + ((a0 + a1) + (a2 + a3));
        float gv = is_g ? tanh_f(pre) : sigmoid_f(pre);
        sh_g[row] = gv;
        __syncthreads();

        // cell update on o-gate threads (their gv == o_j; c_j stays in VGPR)
        if (row >= 3 * H) {
            int j = row - 3 * H;
            float ig = sh_g[j];
            float fg = sh_g[H + j];
            float gg = sh_g[2 * H + j];
            c = fg * c + ig * gg;
            sh_h[j] = (half_t)(gv * tanh_f(c));
        }
        __syncthreads();
        xg_cur = xg_nxt;
    }

    // out = sigmoid(h . W_lin + b_lin)  -- one wave reduces
    if (row < 64) {
        float p = (float)sh_h[row] * Wlin[row] +
                  (float)sh_h[row + 64] * Wlin[row + 64];
#pragma unroll
        for (int off = 32; off > 0; off >>= 1) p += __shfl_down(p, off);
        if (row == 0) out[0] = sigmoid_f(p + blin[0]);
    }
}

extern "C" void kernel_launch(void* const* d_in, const int* in_sizes, int n_in,
                              void* d_out, int out_size, void* d_ws, size_t ws_size,
                              hipStream_t stream)
{
    const float* x    = (const float*)d_in[0];
    const float* Wih  = (const float*)d_in[1];
    const float* Whh  = (const float*)d_in[2];
    const float* bih  = (const float*)d_in[3];
    const float* bhh  = (const float*)d_in[4];
    const float* Wlin = (const float*)d_in[5];
    const float* blin = (const float*)d_in[6];
    float* out = (float*)d_out;

    const size_t need = (size_t)SEQ * G4 * sizeof(float); // 128 MB
    if (ws_size >= need) {
        float* xg = (float*)d_ws;
        xg_gemm<<<(SEQ * G4) / 256, 256, 0, stream>>>(x, Wih, bih, bhh, xg);
        lstm_scan<true><<<1, 512, 0, stream>>>(x, Wih, Whh, bih, bhh, Wlin,
                                               blin, xg, out);
    } else {
        lstm_scan<false><<<1, 512, 0, stream>>>(x, Wih, Whh, bih, bhh, Wlin,
                                                blin, nullptr, out);
    }
}

// Round 3
// 33122.559 us; speedup vs baseline: 1.6138x; 1.1689x over previous
//
#include <hip/hip_runtime.h>

#define SEQ 65536
#define IN_DIM 64
#define H 128
#define G4 512

typedef _Float16 half_t;
typedef half_t half2_t __attribute__((ext_vector_type(2)));
typedef half_t half8_t __attribute__((ext_vector_type(8)));

__device__ __forceinline__ float fast_rcp(float x) { return __builtin_amdgcn_rcpf(x); }

__device__ __forceinline__ float sigmoid_f(float x) {
    x = fminf(fmaxf(x, -30.f), 30.f);
    return fast_rcp(1.f + __expf(-x));
}

__device__ __forceinline__ float tanh_f(float x) {
    x = fminf(fmaxf(x, -15.f), 15.f);
    float e = __expf(2.f * x);
    return (e - 1.f) * fast_rcp(e + 1.f);
}

#if __has_builtin(__builtin_amdgcn_fdot2)
__device__ __forceinline__ float dot2(half2_t a, half2_t b, float c) {
    return __builtin_amdgcn_fdot2(a, b, c, false);
}
#else
__device__ __forceinline__ float dot2(half2_t a, half2_t b, float c) {
    return c + (float)a[0] * (float)b[0] + (float)a[1] * (float)b[1];
}
#endif

__device__ __forceinline__ half2_t pick2(half8_t v, int i0) {
    half2_t r; r[0] = v[i0]; r[1] = v[i0 + 1]; return r;
}

// 8 fp32 -> half8 (two float4 loads)
__device__ __forceinline__ half8_t cvt8(const float* p) {
    float4 a = *(const float4*)p;
    float4 b = *(const float4*)(p + 4);
    half8_t r;
    r[0] = (half_t)a.x; r[1] = (half_t)a.y; r[2] = (half_t)a.z; r[3] = (half_t)a.w;
    r[4] = (half_t)b.x; r[5] = (half_t)b.y; r[6] = (half_t)b.z; r[7] = (half_t)b.w;
    return r;
}

// quad-lane butterfly via DPP (VALU pipe; __shfl_xor would hit the DS pipe)
#if __has_builtin(__builtin_amdgcn_mov_dpp)
__device__ __forceinline__ float qx1(float x) { // lane ^ 1 (quad_perm [1,0,3,2])
    return __int_as_float(__builtin_amdgcn_mov_dpp(__float_as_int(x), 0xB1, 0xF, 0xF, true));
}
__device__ __forceinline__ float qx2(float x) { // lane ^ 2 (quad_perm [2,3,0,1])
    return __int_as_float(__builtin_amdgcn_mov_dpp(__float_as_int(x), 0x4E, 0xF, 0xF, true));
}
#else
__device__ __forceinline__ float qx1(float x) { return __shfl_xor(x, 1, 4); }
__device__ __forceinline__ float qx2(float x) { return __shfl_xor(x, 2, 4); }
#endif

// ---------------------------------------------------------------------------
// Phase A: transposed x_gates.  xg_t[s][j][g] = dot(x[s], W_ih[g*128+j]) + b
// layout index = s*512 + j*4 + g  -> finalize lane reads one float4 per step.
// ---------------------------------------------------------------------------
__global__ __launch_bounds__(256) void xg_gemm(
    const float* __restrict__ x, const float* __restrict__ Wih,
    const float* __restrict__ bih, const float* __restrict__ bhh,
    float* __restrict__ xg)
{
    long long gid = (long long)blockIdx.x * 256 + threadIdx.x;
    int s = (int)(gid >> 9);
    int rr = (int)(gid & 511);
    int j = rr >> 2, g = rr & 3;
    int row = g * H + j;
    const float* xr = x + (long long)s * IN_DIM;
    const float* wr = Wih + (long long)row * IN_DIM;
    float a0 = 0.f, a1 = 0.f, a2 = 0.f, a3 = 0.f;
#pragma unroll
    for (int k = 0; k < IN_DIM; k += 4) {
        float4 iv = *(const float4*)(xr + k);
        float4 wv = *(const float4*)(wr + k);
        a0 += wv.x * iv.x; a1 += wv.y * iv.y;
        a2 += wv.z * iv.z; a3 += wv.w * iv.w;
    }
    xg[gid] = (a0 + a1) + (a2 + a3) + bih[row] + bhh[row];
}

// ---------------------------------------------------------------------------
// Phase B: persistent 256-thread (4-wave) scan.
// Thread tid: quad q = tid>>2 owns j0 = q*2 (2 cell indices j0, j0+1);
// lane-in-quad ql = tid&3 owns col slice [ql*32, ql*32+32).
// Per thread: 8 rows {j0,j0+1}+128*{0..3} x 32 cols of W_hh in 128 f16 VGPRs.
// Step: 4x ds_read_b128 (h slice) -> 128 dot2 -> quad DPP butterfly ->
// lanes ql<2 finalize j=j0+ql fully in registers (acts + cell) -> 1 ds_write
// -> ONE barrier. h double-buffered in LDS (f16).
// ---------------------------------------------------------------------------
__global__ __launch_bounds__(256, 1) void lstm_scan(
    const float* __restrict__ Whh, const float* __restrict__ Wlin,
    const float* __restrict__ blin, const float* __restrict__ xg,
    float* __restrict__ out)
{
    __shared__ __align__(16) half_t shbuf[2][H]; // 512 B double-buffered h
    const int tid = threadIdx.x;
    const int ql = tid & 3;
    const int j0 = (tid >> 2) * 2;
    const int c0 = ql * 32;
    const int jrow = j0 + (ql & 1); // valid for ql<2

    // ---- weights: 8 rows x 32 cols as 32 named half8 (128 VGPRs) ----
#define LOADW(P, ROW)                                                     \
    half8_t P##0 = cvt8(Whh + (size_t)(ROW) * H + c0 + 0),                \
            P##1 = cvt8(Whh + (size_t)(ROW) * H + c0 + 8),                \
            P##2 = cvt8(Whh + (size_t)(ROW) * H + c0 + 16),               \
            P##3 = cvt8(Whh + (size_t)(ROW) * H + c0 + 24);
    LOADW(wi0, j0)           LOADW(wi1, j0 + 1)
    LOADW(wf0, 128 + j0)     LOADW(wf1, 129 + j0)
    LOADW(wg0, 256 + j0)     LOADW(wg1, 257 + j0)
    LOADW(wo0, 384 + j0)     LOADW(wo1, 385 + j0)
#undef LOADW
    // pin: opaque to rematerialization/sinking (the R1/R2 demotion failure)
#define PIN(A, B, C, D) asm volatile("" : "+v"(A), "+v"(B), "+v"(C), "+v"(D))
    PIN(wi00, wi01, wi02, wi03); PIN(wi10, wi11, wi12, wi13);
    PIN(wf00, wf01, wf02, wf03); PIN(wf10, wf11, wf12, wf13);
    PIN(wg00, wg01, wg02, wg03); PIN(wg10, wg11, wg12, wg13);
    PIN(wo00, wo01, wo02, wo03); PIN(wo10, wo11, wo12, wo13);
#undef PIN

    float c = 0.f;
    float4 xgv = {0.f, 0.f, 0.f, 0.f};
    if (ql < 2) xgv = *(const float4*)(xg + (size_t)jrow * 4);
    if (tid < H) shbuf[0][tid] = (half_t)0.f;
    __syncthreads();

#define DOT8(ACC, WV, HV)                                                 \
    ACC = dot2(pick2(WV, 0), pick2(HV, 0), ACC);                          \
    ACC = dot2(pick2(WV, 2), pick2(HV, 2), ACC);                          \
    ACC = dot2(pick2(WV, 4), pick2(HV, 4), ACC);                          \
    ACC = dot2(pick2(WV, 6), pick2(HV, 6), ACC);
#define DOTROW(ACC, P)                                                    \
    DOT8(ACC, P##0, h0) DOT8(ACC, P##1, h1)                               \
    DOT8(ACC, P##2, h2) DOT8(ACC, P##3, h3)
#define QRED(X) X += qx1(X); X += qx2(X);

#define STEP(RB, WB, T)                                                   \
    {                                                                     \
        const half8_t* hp = (const half8_t*)&shbuf[RB][c0];               \
        half8_t h0 = hp[0], h1 = hp[1], h2 = hp[2], h3 = hp[3];           \
        int tn = (T) + 1; if (tn > SEQ - 1) tn = SEQ - 1;                 \
        float4 xg_n = {0.f, 0.f, 0.f, 0.f};                               \
        if (ql < 2)                                                       \
            xg_n = *(const float4*)(xg + (size_t)tn * G4 + jrow * 4);     \
        float ai0 = 0.f, ai1 = 0.f, af0 = 0.f, af1 = 0.f;                 \
        float ag0 = 0.f, ag1 = 0.f, ao0 = 0.f, ao1 = 0.f;                 \
        DOTROW(ai0, wi0) DOTROW(ai1, wi1)                                 \
        DOTROW(af0, wf0) DOTROW(af1, wf1)                                 \
        DOTROW(ag0, wg0) DOTROW(ag1, wg1)                                 \
        DOTROW(ao0, wo0) DOTROW(ao1, wo1)                                 \
        QRED(ai0) QRED(ai1) QRED(af0) QRED(af1)                           \
        QRED(ag0) QRED(ag1) QRED(ao0) QRED(ao1)                           \
        if (ql < 2) {                                                     \
            float si = ql ? ai1 : ai0, sf = ql ? af1 : af0;               \
            float sg = ql ? ag1 : ag0, so = ql ? ao1 : ao0;               \
            float gi = sigmoid_f(si + xgv.x);                             \
            float gf = sigmoid_f(sf + xgv.y);                             \
            float gg = tanh_f(sg + xgv.z);                                \
            float go = sigmoid_f(so + xgv.w);                             \
            c = gf * c + gi * gg;                                         \
            shbuf[WB][jrow] = (half_t)(go * tanh_f(c));                   \
        }                                                                 \
        __syncthreads();                                                  \
        xgv = xg_n;                                                       \
    }

    for (int t = 0; t < SEQ; t += 2) {
        STEP(0, 1, t)
        STEP(1, 0, t + 1)
    }
#undef STEP
#undef QRED
#undef DOTROW
#undef DOT8

    // h(SEQ) is in shbuf[0]; one wave reduces the linear head.
    if (tid < 64) {
        float p = (float)shbuf[0][tid] * Wlin[tid] +
                  (float)shbuf[0][tid + 64] * Wlin[tid + 64];
#pragma unroll
        for (int off = 32; off > 0; off >>= 1) p += __shfl_down(p, off);
        if (tid == 0) out[0] = sigmoid_f(p + blin[0]);
    }
}

// ---------------------------------------------------------------------------
// Fallback (ws too small): round-2 kernel, known correct, no scratch needed.
// ---------------------------------------------------------------------------
__global__ __launch_bounds__(512, 2) void lstm_scan_fb(
    const float* __restrict__ x, const float* __restrict__ Wih,
    const float* __restrict__ Whh, const float* __restrict__ bih,
    const float* __restrict__ bhh, const float* __restrict__ Wlin,
    const float* __restrict__ blin, float* __restrict__ out)
{
    __shared__ __align__(16) half_t sh_h[H];
    __shared__ __align__(16) float  sh_g[G4];
    const int row = threadIdx.x;
    const float* wrow = Whh + (long long)row * H;

    half8_t w0  = cvt8(wrow + 0),   w1  = cvt8(wrow + 8);
    half8_t w2  = cvt8(wrow + 16),  w3  = cvt8(wrow + 24);
    half8_t w4  = cvt8(wrow + 32),  w5  = cvt8(wrow + 40);
    half8_t w6  = cvt8(wrow + 48),  w7  = cvt8(wrow + 56);
    half8_t w8  = cvt8(wrow + 64),  w9  = cvt8(wrow + 72);
    half8_t w10 = cvt8(wrow + 80),  w11 = cvt8(wrow + 88);
    half8_t w12 = cvt8(wrow + 96),  w13 = cvt8(wrow + 104);
    half8_t w14 = cvt8(wrow + 112), w15 = cvt8(wrow + 120);

    const float bsum = bih[row] + bhh[row];
    float c = 0.f;
    if (row < H) sh_h[row] = (half_t)0.f;

    float xg_cur;
    {
        float a = bsum;
        const float* wir = Wih + (long long)row * IN_DIM;
#pragma unroll
        for (int k = 0; k < IN_DIM; k += 4) {
            float4 iv = *(const float4*)(x + k);
            float4 wv = *(const float4*)(wir + k);
            a += wv.x * iv.x + wv.y * iv.y + wv.z * iv.z + wv.w * iv.w;
        }
        xg_cur = a;
    }
    const bool is_g = (row >= 2 * H) && (row < 3 * H);
    __syncthreads();

    const half8_t* hch = (const half8_t*)sh_h;

    for (int t = 0; t < SEQ; ++t) {
        float xg_nxt = 0.f;
        if (t + 1 < SEQ) {
            const float* xr = x + (size_t)(t + 1) * IN_DIM;
            const float* wir = Wih + (long long)row * IN_DIM;
            float a = bsum;
#pragma unroll
            for (int k = 0; k < IN_DIM; k += 4) {
                float4 iv = *(const float4*)(xr + k);
                float4 wv = *(const float4*)(wir + k);
                a += wv.x * iv.x + wv.y * iv.y + wv.z * iv.z + wv.w * iv.w;
            }
            xg_nxt = a;
        }
        float a0 = 0.f, a1 = 0.f, a2 = 0.f, a3 = 0.f;
#define DOTC(WV, CI)                                                     \
        {   half8_t hv = hch[CI];                                        \
            a0 = dot2(pick2(WV, 0), pick2(hv, 0), a0);                   \
            a1 = dot2(pick2(WV, 2), pick2(hv, 2), a1);                   \
            a2 = dot2(pick2(WV, 4), pick2(hv, 4), a2);                   \
            a3 = dot2(pick2(WV, 6), pick2(hv, 6), a3); }
        DOTC(w0, 0)  DOTC(w1, 1)  DOTC(w2, 2)   DOTC(w3, 3)
        DOTC(w4, 4)  DOTC(w5, 5)  DOTC(w6, 6)   DOTC(w7, 7)
        DOTC(w8, 8)  DOTC(w9, 9)  DOTC(w10, 10) DOTC(w11, 11)
        DOTC(w12, 12) DOTC(w13, 13) DOTC(w14, 14) DOTC(w15, 15)
#undef DOTC
        float pre = xg_cur + ((a0 + a1) + (a2 + a3));
        float gv = is_g ? tanh_f(pre) : sigmoid_f(pre);
        sh_g[row] = gv;
        __syncthreads();
        if (row >= 3 * H) {
            int j = row - 3 * H;
            float ig = sh_g[j];
            float fg = sh_g[H + j];
            float gg = sh_g[2 * H + j];
            c = fg * c + ig * gg;
            sh_h[j] = (half_t)(gv * tanh_f(c));
        }
        __syncthreads();
        xg_cur = xg_nxt;
    }

    if (row < 64) {
        float p = (float)sh_h[row] * Wlin[row] +
                  (float)sh_h[row + 64] * Wlin[row + 64];
#pragma unroll
        for (int off = 32; off > 0; off >>= 1) p += __shfl_down(p, off);
        if (row == 0) out[0] = sigmoid_f(p + blin[0]);
    }
}

extern "C" void kernel_launch(void* const* d_in, const int* in_sizes, int n_in,
                              void* d_out, int out_size, void* d_ws, size_t ws_size,
                              hipStream_t stream)
{
    const float* x    = (const float*)d_in[0];
    const float* Wih  = (const float*)d_in[1];
    const float* Whh  = (const float*)d_in[2];
    const float* bih  = (const float*)d_in[3];
    const float* bhh  = (const float*)d_in[4];
    const float* Wlin = (const float*)d_in[5];
    const float* blin = (const float*)d_in[6];
    float* out = (float*)d_out;

    const size_t need = (size_t)SEQ * G4 * sizeof(float); // 128 MB
    if (ws_size >= need) {
        float* xg = (float*)d_ws;
        xg_gemm<<<(SEQ * G4) / 256, 256, 0, stream>>>(x, Wih, bih, bhh, xg);
        lstm_scan<<<1, 256, 0, stream>>>(Whh, Wlin, blin, xg, out);
    } else {
        lstm_scan_fb<<<1, 512, 0, stream>>>(x, Wih, Whh, bih, bhh, Wlin,
                                            blin, out);
    }
}

// Round 5
// 32302.856 us; speedup vs baseline: 1.6548x; 1.0254x over previous
//
#include <hip/hip_runtime.h>

#define SEQ 65536
#define IN_DIM 64
#define H 128
#define G4 512

typedef _Float16 half_t;
typedef half_t half2_t __attribute__((ext_vector_type(2)));
typedef half_t half8_t __attribute__((ext_vector_type(8)));

__device__ __forceinline__ float fast_rcp(float x) { return __builtin_amdgcn_rcpf(x); }

__device__ __forceinline__ float sigmoid_f(float x) {
    x = fminf(fmaxf(x, -30.f), 30.f);
    return fast_rcp(1.f + __expf(-x));
}

#if __has_builtin(__builtin_amdgcn_fdot2)
__device__ __forceinline__ float dot2(half2_t a, half2_t b, float c) {
    return __builtin_amdgcn_fdot2(a, b, c, false);
}
#else
__device__ __forceinline__ float dot2(half2_t a, half2_t b, float c) {
    return c + (float)a[0] * (float)b[0] + (float)a[1] * (float)b[1];
}
#endif

__device__ __forceinline__ half2_t pick2(half8_t v, int i0) {
    half2_t r; r[0] = v[i0]; r[1] = v[i0 + 1]; return r;
}

// 8 fp32 -> half8 (two float4 loads)
__device__ __forceinline__ half8_t cvt8(const float* p) {
    float4 a = *(const float4*)p;
    float4 b = *(const float4*)(p + 4);
    half8_t r;
    r[0] = (half_t)a.x; r[1] = (half_t)a.y; r[2] = (half_t)a.z; r[3] = (half_t)a.w;
    r[4] = (half_t)b.x; r[5] = (half_t)b.y; r[6] = (half_t)b.z; r[7] = (half_t)b.w;
    return r;
}

// quad-lane exchanges via DPP (VALU pipe; __shfl_xor would hit the DS pipe).
// DPP control MUST be a compile-time constant -> template parameter.
template <int CTRL>
__device__ __forceinline__ float qperm(float x) {
    return __int_as_float(
        __builtin_amdgcn_mov_dpp(__float_as_int(x), CTRL, 0xF, 0xF, true));
}
#define qx1(x)  qperm<0xB1>(x) /* quad_perm [1,0,3,2] lane^1 */
#define qx2(x)  qperm<0x4E>(x) /* quad_perm [2,3,0,1] lane^2 */
#define qrev(x) qperm<0x1B>(x) /* quad_perm [3,2,1,0] lane^3 */

// ---------------------------------------------------------------------------
// Phase A: xg[s][row] = dot(x[s], W_ih[row]) + b_ih[row] + b_hh[row]
// row = g*128 + j (natural layout) -> finalize lane (gate g, cells j0,j0+1)
// reads one float2 at xg + s*512 + g*128 + j0.
// ---------------------------------------------------------------------------
__global__ __launch_bounds__(256) void xg_gemm(
    const float* __restrict__ x, const float* __restrict__ Wih,
    const float* __restrict__ bih, const float* __restrict__ bhh,
    float* __restrict__ xg)
{
    long long gid = (long long)blockIdx.x * 256 + threadIdx.x;
    int s = (int)(gid >> 9);
    int r = (int)(gid & 511);
    const float* xr = x + (long long)s * IN_DIM;
    const float* wr = Wih + (long long)r * IN_DIM;
    float a0 = 0.f, a1 = 0.f, a2 = 0.f, a3 = 0.f;
#pragma unroll
    for (int k = 0; k < IN_DIM; k += 4) {
        float4 iv = *(const float4*)(xr + k);
        float4 wv = *(const float4*)(wr + k);
        a0 += wv.x * iv.x; a1 += wv.y * iv.y;
        a2 += wv.z * iv.z; a3 += wv.w * iv.w;
    }
    xg[gid] = (a0 + a1) + (a2 + a3) + bih[r] + bhh[r];
}

// ---------------------------------------------------------------------------
// Phase B: persistent 256-thread (4-wave) scan.
// Quad q owns cells {j0, j0+1}, lane ql owns cols [ql*32, ql*32+32).
// Per step: 4x ds_read_b128 (h slice) -> 128 dot2 (8 acc chains) -> quad DPP
// butterfly (all lanes get all 8 sums) -> GATE-PARALLEL finalize: lane ql
// applies gate ql's activation for both cells; DPP gathers route i,f,g,o
// to cell-owner lanes 0,1 which update c in-register -> masked ds_write ->
// raw s_barrier with lgkmcnt-only drain (xg prefetch loads, depth 2, ride
// ACROSS the barrier -- __syncthreads would vmcnt(0)-drain them every step).
// ---------------------------------------------------------------------------
__global__ __launch_bounds__(256, 1) void lstm_scan(
    const float* __restrict__ Whh, const float* __restrict__ Wlin,
    const float* __restrict__ blin, const float* __restrict__ xg,
    float* __restrict__ out)
{
    __shared__ __align__(16) half_t shbuf[2][H]; // 512 B double-buffered h
    const int tid = threadIdx.x;
    const int ql = tid & 3;
    const int j0 = (tid >> 2) * 2;
    const int c0 = ql * 32;

    // ---- weights: 8 rows x 32 cols as 32 named half8 (64 VGPRs) ----
#define LOADW(P, ROW)                                                     \
    half8_t P##0 = cvt8(Whh + (size_t)(ROW) * H + c0 + 0),                \
            P##1 = cvt8(Whh + (size_t)(ROW) * H + c0 + 8),                \
            P##2 = cvt8(Whh + (size_t)(ROW) * H + c0 + 16),               \
            P##3 = cvt8(Whh + (size_t)(ROW) * H + c0 + 24);
    LOADW(wi0, j0)           LOADW(wi1, j0 + 1)
    LOADW(wf0, 128 + j0)     LOADW(wf1, 129 + j0)
    LOADW(wg0, 256 + j0)     LOADW(wg1, 257 + j0)
    LOADW(wo0, 384 + j0)     LOADW(wo1, 385 + j0)
#undef LOADW
#define PIN(A, B, C, D) asm volatile("" : "+v"(A), "+v"(B), "+v"(C), "+v"(D))
    PIN(wi00, wi01, wi02, wi03); PIN(wi10, wi11, wi12, wi13);
    PIN(wf00, wf01, wf02, wf03); PIN(wf10, wf11, wf12, wf13);
    PIN(wg00, wg01, wg02, wg03); PIN(wg10, wg11, wg12, wg13);
    PIN(wo00, wo01, wo02, wo03); PIN(wo10, wo11, wo12, wo13);
#undef PIN

    const bool isg = (ql == 2);
    const bool l0  = (ql == 0);
    const float* xgbase = xg + ql * H + j0; // [s][gate][j] pair for this lane
    float c = 0.f;

    // xg ring: depth-2 prefetch (window ~2 steps > HBM-miss latency)
    float2 xg_c = *(const float2*)(xgbase + (size_t)0 * G4);
    float2 xg_n = *(const float2*)(xgbase + (size_t)1 * G4);

    if (tid < H) shbuf[0][tid] = (half_t)0.f;
    __syncthreads();

#define DOT8(ACC, WV, HV)                                                 \
    ACC = dot2(pick2(WV, 0), pick2(HV, 0), ACC);                          \
    ACC = dot2(pick2(WV, 2), pick2(HV, 2), ACC);                          \
    ACC = dot2(pick2(WV, 4), pick2(HV, 4), ACC);                          \
    ACC = dot2(pick2(WV, 6), pick2(HV, 6), ACC);
#define DOTROW(ACC, P)                                                    \
    DOT8(ACC, P##0, h0) DOT8(ACC, P##1, h1)                               \
    DOT8(ACC, P##2, h2) DOT8(ACC, P##3, h3)
#define QRED(X) X += qx1(X); X += qx2(X);

#define STEP(RB, WB, T)                                                   \
    {                                                                     \
        const half8_t* hp = (const half8_t*)&shbuf[RB][c0];               \
        half8_t h0 = hp[0], h1 = hp[1], h2 = hp[2], h3 = hp[3];           \
        int tp = (T) + 2; if (tp > SEQ - 1) tp = SEQ - 1;                 \
        float2 xg_p = *(const float2*)(xgbase + (size_t)tp * G4);         \
        float ai0 = 0.f, ai1 = 0.f, af0 = 0.f, af1 = 0.f;                 \
        float ag0 = 0.f, ag1 = 0.f, ao0 = 0.f, ao1 = 0.f;                 \
        DOTROW(ai0, wi0) DOTROW(ai1, wi1)                                 \
        DOTROW(af0, wf0) DOTROW(af1, wf1)                                 \
        DOTROW(ag0, wg0) DOTROW(ag1, wg1)                                 \
        DOTROW(ao0, wo0) DOTROW(ao1, wo1)                                 \
        QRED(ai0) QRED(ai1) QRED(af0) QRED(af1)                           \
        QRED(ag0) QRED(ag1) QRED(ao0) QRED(ao1)                           \
        /* lane ql selects gate-ql sums for both cells */                 \
        float sa = ai0, sb = ai1;                                         \
        if (ql == 1) { sa = af0; sb = af1; }                              \
        if (ql == 2) { sa = ag0; sb = ag1; }                              \
        if (ql == 3) { sa = ao0; sb = ao1; }                              \
        float xa = sa + xg_c.x, xb = sb + xg_c.y;                         \
        float ua = isg ? xa + xa : xa;                                    \
        float ub = isg ? xb + xb : xb;                                    \
        float ra = sigmoid_f(ua), rb = sigmoid_f(ub);                     \
        float gva = isg ? ra + ra - 1.f : ra;  /* tanh = 2s(2x)-1 */      \
        float gvb = isg ? rb + rb - 1.f : rb;                             \
        /* route i,f,g,o to cell-owner lanes 0 (cell j0) and 1 (j0+1) */  \
        float fA = qx1(gva), iB = qx1(gvb);                               \
        float gA = qx2(gva), oB = qx2(gvb);                               \
        float oA = qrev(gva), gB = qrev(gvb);                             \
        float ii = l0 ? gva : iB;                                         \
        float ff = l0 ? fA  : gvb;                                        \
        float gg = l0 ? gA  : gB;                                         \
        float oo = l0 ? oA  : oB;                                         \
        c = ff * c + ii * gg;                                             \
        float th = 2.f * sigmoid_f(c + c) - 1.f;                          \
        float hh = oo * th;                                               \
        if (ql < 2) shbuf[WB][j0 + ql] = (half_t)hh;                      \
        asm volatile("s_waitcnt lgkmcnt(0)" ::: "memory");                \
        __builtin_amdgcn_s_barrier();                                     \
        __builtin_amdgcn_sched_barrier(0);                                \
        xg_c = xg_n; xg_n = xg_p;                                         \
    }

    for (int t = 0; t < SEQ; t += 2) {
        STEP(0, 1, t)
        STEP(1, 0, t + 1)
    }
#undef STEP
#undef QRED
#undef DOTROW
#undef DOT8

    // h(SEQ) is in shbuf[0]; one wave reduces the linear head.
    if (tid < 64) {
        float p = (float)shbuf[0][tid] * Wlin[tid] +
                  (float)shbuf[0][tid + 64] * Wlin[tid + 64];
#pragma unroll
        for (int off = 32; off > 0; off >>= 1) p += __shfl_down(p, off);
        if (tid == 0) out[0] = sigmoid_f(p + blin[0]);
    }
}

// ---------------------------------------------------------------------------
// Fallback (ws too small): round-2 kernel, known correct, no scratch needed.
// ---------------------------------------------------------------------------
__global__ __launch_bounds__(512, 2) void lstm_scan_fb(
    const float* __restrict__ x, const float* __restrict__ Wih,
    const float* __restrict__ Whh, const float* __restrict__ bih,
    const float* __restrict__ bhh, const float* __restrict__ Wlin,
    const float* __restrict__ blin, float* __restrict__ out)
{
    __shared__ __align__(16) half_t sh_h[H];
    __shared__ __align__(16) float  sh_g[G4];
    const int row = threadIdx.x;
    const float* wrow = Whh + (long long)row * H;

    half8_t w0  = cvt8(wrow + 0),   w1  = cvt8(wrow + 8);
    half8_t w2  = cvt8(wrow + 16),  w3  = cvt8(wrow + 24);
    half8_t w4  = cvt8(wrow + 32),  w5  = cvt8(wrow + 40);
    half8_t w6  = cvt8(wrow + 48),  w7  = cvt8(wrow + 56);
    half8_t w8  = cvt8(wrow + 64),  w9  = cvt8(wrow + 72);
    half8_t w10 = cvt8(wrow + 80),  w11 = cvt8(wrow + 88);
    half8_t w12 = cvt8(wrow + 96),  w13 = cvt8(wrow + 104);
    half8_t w14 = cvt8(wrow + 112), w15 = cvt8(wrow + 120);

    const float bsum = bih[row] + bhh[row];
    float c = 0.f;
    if (row < H) sh_h[row] = (half_t)0.f;

    float xg_cur;
    {
        float a = bsum;
        const float* wir = Wih + (long long)row * IN_DIM;
#pragma unroll
        for (int k = 0; k < IN_DIM; k += 4) {
            float4 iv = *(const float4*)(x + k);
            float4 wv = *(const float4*)(wir + k);
            a += wv.x * iv.x + wv.y * iv.y + wv.z * iv.z + wv.w * iv.w;
        }
        xg_cur = a;
    }
    const bool is_g = (row >= 2 * H) && (row < 3 * H);
    __syncthreads();

    const half8_t* hch = (const half8_t*)sh_h;

    for (int t = 0; t < SEQ; ++t) {
        float xg_nxt = 0.f;
        if (t + 1 < SEQ) {
            const float* xr = x + (size_t)(t + 1) * IN_DIM;
            const float* wir = Wih + (long long)row * IN_DIM;
            float a = bsum;
#pragma unroll
            for (int k = 0; k < IN_DIM; k += 4) {
                float4 iv = *(const float4*)(xr + k);
                float4 wv = *(const float4*)(wir + k);
                a += wv.x * iv.x + wv.y * iv.y + wv.z * iv.z + wv.w * iv.w;
            }
            xg_nxt = a;
        }
        float a0 = 0.f, a1 = 0.f, a2 = 0.f, a3 = 0.f;
#define DOTC(WV, CI)                                                     \
        {   half8_t hv = hch[CI];                                        \
            a0 = dot2(pick2(WV, 0), pick2(hv, 0), a0);                   \
            a1 = dot2(pick2(WV, 2), pick2(hv, 2), a1);                   \
            a2 = dot2(pick2(WV, 4), pick2(hv, 4), a2);                   \
            a3 = dot2(pick2(WV, 6), pick2(hv, 6), a3); }
        DOTC(w0, 0)  DOTC(w1, 1)  DOTC(w2, 2)   DOTC(w3, 3)
        DOTC(w4, 4)  DOTC(w5, 5)  DOTC(w6, 6)   DOTC(w7, 7)
        DOTC(w8, 8)  DOTC(w9, 9)  DOTC(w10, 10) DOTC(w11, 11)
        DOTC(w12, 12) DOTC(w13, 13) DOTC(w14, 14) DOTC(w15, 15)
#undef DOTC
        float pre = xg_cur + ((a0 + a1) + (a2 + a3));
        float gv;
        if (is_g) {
            float s = sigmoid_f(pre + pre);
            gv = s + s - 1.f;
        } else {
            gv = sigmoid_f(pre);
        }
        sh_g[row] = gv;
        __syncthreads();
        if (row >= 3 * H) {
            int j = row - 3 * H;
            float ig = sh_g[j];
            float fg = sh_g[H + j];
            float gg = sh_g[2 * H + j];
            c = fg * c + ig * gg;
            float s = sigmoid_f(c + c);
            sh_h[j] = (half_t)(gv * (s + s - 1.f));
        }
        __syncthreads();
        xg_cur = xg_nxt;
    }

    if (row < 64) {
        float p = (float)sh_h[row] * Wlin[row] +
                  (float)sh_h[row + 64] * Wlin[row + 64];
#pragma unroll
        for (int off = 32; off > 0; off >>= 1) p += __shfl_down(p, off);
        if (row == 0) out[0] = sigmoid_f(p + blin[0]);
    }
}

extern "C" void kernel_launch(void* const* d_in, const int* in_sizes, int n_in,
                              void* d_out, int out_size, void* d_ws, size_t ws_size,
                              hipStream_t stream)
{
    const float* x    = (const float*)d_in[0];
    const float* Wih  = (const float*)d_in[1];
    const float* Whh  = (const float*)d_in[2];
    const float* bih  = (const float*)d_in[3];
    const float* bhh  = (const float*)d_in[4];
    const float* Wlin = (const float*)d_in[5];
    const float* blin = (const float*)d_in[6];
    float* out = (float*)d_out;

    const size_t need = (size_t)SEQ * G4 * sizeof(float); // 128 MB
    if (ws_size >= need) {
        float* xg = (float*)d_ws;
        xg_gemm<<<(SEQ * G4) / 256, 256, 0, stream>>>(x, Wih, bih, bhh, xg);
        lstm_scan<<<1, 256, 0, stream>>>(Whh, Wlin, blin, xg, out);
    } else {
        lstm_scan_fb<<<1, 512, 0, stream>>>(x, Wih, Whh, bih, bhh, Wlin,
                                            blin, out);
    }
}